// Round 1
// baseline (408.993 us; speedup 1.0000x reference)
//
#include <hip/hip_runtime.h>
#include <stdint.h>

typedef __bf16 bf16x8 __attribute__((ext_vector_type(8)));
typedef float f32x4 __attribute__((ext_vector_type(4)));
typedef unsigned short u16;

__device__ __forceinline__ u16 f2bf(float f){
  uint32_t u = __float_as_uint(f);
  u = (u + 0x7fffu + ((u >> 16) & 1u)) >> 16;
  return (u16)u;
}

__device__ __forceinline__ void gl_lds16(const void* g, void* l){
  __builtin_amdgcn_global_load_lds((const __attribute__((address_space(1))) void*)g,
                                   (__attribute__((address_space(3))) void*)l, 16, 0, 0);
}

// ---------------------------------------------------------------------------
// Weight prep: f32 -> bf16 (w1 [256][1024], w3 [1024][256] straight copy)
// ---------------------------------------------------------------------------
__global__ void cvt_f32_bf16(const float* __restrict__ in, u16* __restrict__ out, int n){
  int i = blockIdx.x*256 + threadIdx.x;
  if (i < n) out[i] = f2bf(in[i]);
}

// w2 [O=256][C=256][3][3] f32  ->  wb2 [O][kq=ky*3+kx][C] bf16  (K order = (kq, c))
__global__ void prep_w2k(const float* __restrict__ in, u16* __restrict__ out){
  int i = blockIdx.x*256 + threadIdx.x;
  if (i < 589824){
    int o = i / 2304, r = i - o*2304, kq = r >> 8, c = r & 255;
    out[i] = f2bf(in[((size_t)o*256 + c)*9 + kq]);
  }
}

// ---------------------------------------------------------------------------
// x [128][1024][196] f32 (NCHW)  ->  xp0 [128][196][1024] bf16 (NHWC, unpadded)
// LDS transpose per (batch, 64-channel chunk)
// ---------------------------------------------------------------------------
__global__ __launch_bounds__(256) void transform_x(const float* __restrict__ x,
                                                   u16* __restrict__ xp0){
  __shared__ float lds[64*197];
  int b = blockIdx.x, t = threadIdx.x;
  for (int cc = 0; cc < 16; ++cc){
    int c0 = cc*64;
    __syncthreads();
    #pragma unroll 7
    for (int r = 0; r < 49; ++r){
      int lin = r*256 + t;            // < 12544 = 64*196
      int c = lin / 196, p = lin - c*196;
      lds[c*197 + p] = x[(size_t)b*200704 + (size_t)c0*196 + lin];
    }
    __syncthreads();
    int c = t & 63, pg = t >> 6;
    #pragma unroll 7
    for (int r = 0; r < 49; ++r){
      int p = r*4 + pg;
      xp0[((size_t)b*196 + p)*1024 + c0 + c] = f2bf(lds[c*197 + p]);
    }
  }
}

// ---------------------------------------------------------------------------
// Unified MFMA GEMM: C[m][n] = sum_k A[m][k] * B[k][n]
//   A = weights bf16 [M][KTOT] row-major (k-contiguous)
//   B = activations bf16 NHWC: columns n = (b, y, x) on padded 16x16 grid
// BM=BN=128, BK=64, 4 waves (2x2 of 64x64), 2-phase global_load_lds double-buffer,
// XOR-swizzle (granule ^= row&7) applied identically on staging-src and ds_read.
// ---------------------------------------------------------------------------
template<int CID>
__global__ __launch_bounds__(256, 2) void gemm_k(
    const u16* __restrict__ A, const u16* __restrict__ B,
    u16* __restrict__ Obf, float* __restrict__ Of32, const float* __restrict__ xres,
    const float* __restrict__ s0, const float* __restrict__ s1, const float* __restrict__ s2)
{
  constexpr int KTOT  = (CID==1) ? 1024 : (CID==2) ? 2304 : 256;
  constexpr int NSTEP = KTOT / 64;

  __shared__ char lds[65536];                 // 2 bufs x (A 16KB + B 16KB)
  const int t    = threadIdx.x;
  const int lane = t & 63;
  const int w    = t >> 6;
  const int wm   = (w >> 1) * 64, wn = (w & 1) * 64;
  const int m0   = blockIdx.y * 128, n0 = blockIdx.x * 128;

  f32x4 acc[4][4] = {};

  auto stage = [&](int buf, int s){
    char* Ab = lds + buf*32768;
    char* Bb = Ab + 16384;
    const int k0 = s*64;
    int shift = 0, c0 = 0;
    if constexpr (CID==2){
      int kq = s >> 2; c0 = (s & 3) * 64;
      shift = (kq/3 - 1)*16 + (kq%3 - 1);
    }
    #pragma unroll
    for (int i = 0; i < 4; ++i){
      int gl  = i*256 + t;                    // granule index in [0,1024)
      int row = gl >> 3, ss = gl & 7;
      int xo  = (ss ^ (row & 7)) << 4;        // swizzled 16B granule byte offset
      // A tile: rows = m, k-window [k0,k0+64)
      gl_lds16((const char*)A + (((size_t)(m0+row))*KTOT + k0)*2 + xo, Ab + gl*16);
      // B tile: rows = n (LDS stores [n_local][64k], k-contiguous)
      int n = n0 + row;
      const char* bsrc;
      if constexpr (CID==1){
        int y = (n >> 4) & 15, xx = n & 15;
        int p = ((unsigned)(y-1) < 14u && (unsigned)(xx-1) < 14u) ? (y-1)*14 + (xx-1) : 0;
        int b = n >> 8;
        bsrc = (const char*)B + (((size_t)b*196 + p)*1024 + k0)*2 + xo;
      } else if constexpr (CID==2){
        bsrc = (const char*)B + (long)(n + shift)*512 + (long)c0*2 + xo;
      } else {
        bsrc = (const char*)B + ((size_t)n*256 + k0)*2 + xo;
      }
      gl_lds16(bsrc, Bb + gl*16);
    }
  };

  auto compute = [&](int buf){
    char* Ab = lds + buf*32768;
    char* Bb = Ab + 16384;
    #pragma unroll
    for (int h = 0; h < 2; ++h){
      bf16x8 af[4], bfr[4];
      #pragma unroll
      for (int i = 0; i < 4; ++i){
        int row = wm + i*16 + (lane & 15);
        af[i] = *(const bf16x8*)(Ab + row*128 + (((h*4 + (lane>>4)) ^ (row & 7)) << 4));
      }
      #pragma unroll
      for (int j = 0; j < 4; ++j){
        int row = wn + j*16 + (lane & 15);
        bfr[j] = *(const bf16x8*)(Bb + row*128 + (((h*4 + (lane>>4)) ^ (row & 7)) << 4));
      }
      #pragma unroll
      for (int i = 0; i < 4; ++i)
        #pragma unroll
        for (int j = 0; j < 4; ++j)
          acc[i][j] = __builtin_amdgcn_mfma_f32_16x16x32_bf16(af[i], bfr[j], acc[i][j], 0, 0, 0);
    }
  };

  stage(0, 0);
  __syncthreads();                            // drains vmcnt(0) before barrier
  for (int s = 0; s < NSTEP; ++s){
    if (s + 1 < NSTEP) stage((s+1) & 1, s+1);
    compute(s & 1);
    __syncthreads();
  }

  // ---- epilogue (C/D: col=lane&15 -> n, row=(lane>>4)*4+q -> m) ----
  if constexpr (CID==1 || CID==2){
    float badd = s0[0] + s1[0];
    #pragma unroll
    for (int i = 0; i < 4; ++i){
      int o = m0 + wm + i*16 + ((lane >> 4) << 2);
      #pragma unroll
      for (int j = 0; j < 4; ++j){
        int n = n0 + wn + j*16 + (lane & 15);
        bool keep = true;
        if constexpr (CID==1){                 // conv2 input border must be exactly 0
          int y = (n >> 4) & 15, xx = n & 15;
          keep = ((unsigned)(y-1) < 14u) && ((unsigned)(xx-1) < 14u);
        }
        ushort4 pk;
        #pragma unroll
        for (int q = 0; q < 4; ++q){
          float v = keep ? (acc[i][j][q] + badd) : 0.f;
          ((u16*)&pk)[q] = f2bf(v);
        }
        *(ushort4*)((char*)Obf + ((size_t)n*256 + (size_t)o)*2) = pk;
      }
    }
  } else {
    float b3 = s0[0], rs = s1[0], rb = s2[0];
    #pragma unroll
    for (int i = 0; i < 4; ++i){
      int o = m0 + wm + i*16 + ((lane >> 4) << 2);
      #pragma unroll
      for (int j = 0; j < 4; ++j){
        int n = n0 + wn + j*16 + (lane & 15);
        int b = n >> 8, y = (n >> 4) & 15, xx = n & 15;
        if (((unsigned)(y-1) < 14u) && ((unsigned)(xx-1) < 14u)){
          int p = (y-1)*14 + (xx-1);
          size_t base = ((size_t)b*1024 + o)*196 + p;
          #pragma unroll
          for (int q = 0; q < 4; ++q){
            float v = (acc[i][j][q] + b3)*rs + rb + xres[base + (size_t)q*196];
            Of32[base + (size_t)q*196] = fmaxf(v, 0.f);
          }
        }
      }
    }
  }
}

// ---------------------------------------------------------------------------
extern "C" void kernel_launch(void* const* d_in, const int* in_sizes, int n_in,
                              void* d_out, int out_size, void* d_ws, size_t ws_size,
                              hipStream_t stream){
  (void)in_sizes; (void)n_in; (void)out_size; (void)ws_size;
  const float* x   = (const float*)d_in[0];
  const float* w1  = (const float*)d_in[1];
  const float* w2  = (const float*)d_in[2];
  const float* w3  = (const float*)d_in[3];
  const float* b1b = (const float*)d_in[4];
  const float* b2a = (const float*)d_in[5];
  const float* b2b = (const float*)d_in[6];
  const float* b3a = (const float*)d_in[7];
  const float* b3b = (const float*)d_in[8];
  const float* rsc = (const float*)d_in[9];
  const float* rbi = (const float*)d_in[10];

  // ws layout (bytes):
  //   [0, 16809984)      xp1 region: 32-row guard | 32768 rows x 512B | 32-row guard
  //   [16809984, +16.8M) xp2: 32768 rows x 512B
  //   then wb1 (512KB), wb2 (1.125MB), wb3 (512KB)   -- total ~35.8 MB
  char* ws   = (char*)d_ws;
  u16*  xp1  = (u16*)ws + 32*256;                  // conv2 input (padded-grid NHWC)
  u16*  xp2  = (u16*)(ws + 16809984);              // conv3 input
  u16*  wb1  = (u16*)(ws + 33587200);
  u16*  wb2  = (u16*)(ws + 34111488);
  u16*  wb3  = (u16*)(ws + 35291136);
  u16*  xp0  = (u16*)d_out;                        // conv1 input staged in d_out (dead before conv3 writes)

  cvt_f32_bf16<<<dim3(1024), 256, 0, stream>>>(w1, wb1, 262144);
  prep_w2k   <<<dim3(2304), 256, 0, stream>>>(w2, wb2);
  cvt_f32_bf16<<<dim3(1024), 256, 0, stream>>>(w3, wb3, 262144);
  transform_x<<<dim3(128),  256, 0, stream>>>(x, xp0);

  gemm_k<1><<<dim3(256, 2), 256, 0, stream>>>(wb1, xp0, xp1, nullptr, nullptr, b1b, b2a, nullptr);
  gemm_k<2><<<dim3(256, 2), 256, 0, stream>>>(wb2, xp1, xp2, nullptr, nullptr, b2b, b3a, nullptr);
  gemm_k<3><<<dim3(256, 8), 256, 0, stream>>>(wb3, xp2, nullptr, (float*)d_out, x, b3b, rsc, rbi);
}

// Round 2
// 339.438 us; speedup vs baseline: 1.2049x; 1.2049x over previous
//
#include <hip/hip_runtime.h>
#include <stdint.h>

typedef __bf16 bf16x8 __attribute__((ext_vector_type(8)));
typedef float f32x4 __attribute__((ext_vector_type(4)));
typedef unsigned short u16;

__device__ __forceinline__ u16 f2bf(float f){
  uint32_t u = __float_as_uint(f);
  u = (u + 0x7fffu + ((u >> 16) & 1u)) >> 16;
  return (u16)u;
}

__device__ __forceinline__ void gl_lds16(const void* g, void* l){
  __builtin_amdgcn_global_load_lds((const __attribute__((address_space(1))) void*)g,
                                   (__attribute__((address_space(3))) void*)l, 16, 0, 0);
}

// ---------------------------------------------------------------------------
// Weight prep
// ---------------------------------------------------------------------------
__global__ void cvt_f32_bf16(const float* __restrict__ in, u16* __restrict__ out, int n){
  int i = blockIdx.x*256 + threadIdx.x;
  if (i < n) out[i] = f2bf(in[i]);
}

// w2 [O=256][C=256][3][3] f32 -> wb2 [O][kq=ky*3+kx][C] bf16
__global__ void prep_w2k(const float* __restrict__ in, u16* __restrict__ out){
  int i = blockIdx.x*256 + threadIdx.x;
  if (i < 589824){
    int o = i / 2304, r = i - o*2304, kq = r >> 8, c = r & 255;
    out[i] = f2bf(in[((size_t)o*256 + c)*9 + kq]);
  }
}

// ---------------------------------------------------------------------------
// x [128][1024][196] f32 NCHW -> xp0 [b*196+p][1024] bf16 (NHWC, real positions)
// grid (16 channel-chunks, 128 batches)
// ---------------------------------------------------------------------------
__global__ __launch_bounds__(256) void transform_x(const float* __restrict__ x,
                                                   u16* __restrict__ xp0){
  __shared__ float lds[64*201];
  const int b = blockIdx.y, c0 = blockIdx.x*64, t = threadIdx.x;
  const float4* src = (const float4*)x + (size_t)b*50176 + (size_t)c0*49;
  #pragma unroll
  for (int r = 0; r < 13; ++r){
    int q = r*256 + t;                 // 3136 float4 = 64ch x 49
    if (q < 3136){
      unsigned c = (unsigned)q / 49u, f = (unsigned)q - c*49u;
      float4 v = src[q];
      float* d = &lds[c*201 + f*4];
      d[0]=v.x; d[1]=v.y; d[2]=v.z; d[3]=v.w;
    }
  }
  __syncthreads();
  const int c4 = (t & 15)*4, pg = t >> 4;
  #pragma unroll
  for (int r = 0; r < 13; ++r){
    int p = r*16 + pg;
    if (p < 196){
      ushort4 pk;
      ((u16*)&pk)[0] = f2bf(lds[(c4+0)*201 + p]);
      ((u16*)&pk)[1] = f2bf(lds[(c4+1)*201 + p]);
      ((u16*)&pk)[2] = f2bf(lds[(c4+2)*201 + p]);
      ((u16*)&pk)[3] = f2bf(lds[(c4+3)*201 + p]);
      *(ushort4*)&xp0[((size_t)b*196 + p)*1024 + c0 + c4] = pk;
    }
  }
}

// ---------------------------------------------------------------------------
// Zero conv2's SAME-padding border rows of xp1 (60 rows per batch x 512B)
// ---------------------------------------------------------------------------
__global__ void zfill_borders(u16* __restrict__ xp1){
  int tid = blockIdx.x*256 + threadIdx.x;     // 960*256 = 245760 = 7680 rows * 32
  int row_i = tid >> 5, w = tid & 31;
  unsigned b = (unsigned)row_i / 60u, k = (unsigned)row_i - b*60u;
  int y, xx;
  if (k < 32){ y = (k>>4)*15; xx = k & 15; }
  else if (k < 46){ y = k - 31; xx = 0; }
  else { y = k - 45; xx = 15; }
  size_t row = (size_t)b*256 + y*16 + xx;
  ((ulonglong2*)(xp1 + row*256))[w] = (ulonglong2){0,0};
}

// ---------------------------------------------------------------------------
// MFMA GEMM: C[m][n] = sum_k A[m][k]*B[k][n]; columns n = real positions (b,p)
// BM=BN=128, BK=64, 4 waves (2x2 of 64x64), double-buffered global_load_lds,
// XOR swizzle (granule ^= row&7) on staging src + ds_read.
// ---------------------------------------------------------------------------
template<int CID>
__global__ __launch_bounds__(256, 2) void gemm_k(
    const u16* __restrict__ A, const u16* __restrict__ B,
    u16* __restrict__ Obf, float* __restrict__ Of32, const float* __restrict__ xres,
    const float* __restrict__ s0, const float* __restrict__ s1, const float* __restrict__ s2)
{
  constexpr int KTOT  = (CID==1) ? 1024 : (CID==2) ? 2304 : 256;
  constexpr int NSTEP = KTOT / 64;

  __shared__ char lds[65536];
  const int t    = threadIdx.x;
  const int lane = t & 63;
  const int w    = t >> 6;
  const int wm   = (w >> 1) * 64, wn = (w & 1) * 64;
  const int m0   = blockIdx.y * 128, n0 = blockIdx.x * 128;

  f32x4 acc[4][4] = {};

  // Precompute per-thread staging source offsets (4 granule-rows each for A,B)
  uint32_t aoff[4], boff[4];
  #pragma unroll
  for (int i = 0; i < 4; ++i){
    int gl = i*256 + t, row = gl >> 3, ss = gl & 7;
    int xo = (ss ^ (row & 7)) << 4;
    aoff[i] = (uint32_t)(m0 + row) * (KTOT*2) + xo;
    uint32_t n = n0 + row;
    if constexpr (CID==1)      boff[i] = n * 2048u + xo;
    else if constexpr (CID==3) boff[i] = n * 512u + xo;
    else {
      uint32_t b = n / 196u, p = n - b*196u;
      uint32_t py = p / 14u,  px = p - py*14u;
      uint32_t prow = b*256u + (py+1)*16u + (px+1);
      boff[i] = prow * 512u + xo;
    }
  }

  auto stage = [&](int buf, int s){
    char* Ab = lds + buf*32768;
    char* Bb = Ab + 16384;
    const int ka = s*128;
    int kb;
    if constexpr (CID==2){
      int kq = s >> 2;
      kb = ((kq/3 - 1)*16 + (kq%3) - 1)*512 + (s & 3)*128;
    } else kb = ka;
    #pragma unroll
    for (int i = 0; i < 4; ++i){
      int gl = i*256 + t;
      gl_lds16((const char*)A + aoff[i] + ka, Ab + gl*16);
      gl_lds16((const char*)B + (int64_t)boff[i] + kb, Bb + gl*16);
    }
  };

  auto compute = [&](int buf){
    char* Ab = lds + buf*32768;
    char* Bb = Ab + 16384;
    #pragma unroll
    for (int h = 0; h < 2; ++h){
      bf16x8 af[4], bfr[4];
      #pragma unroll
      for (int i = 0; i < 4; ++i){
        int row = wm + i*16 + (lane & 15);
        af[i] = *(const bf16x8*)(Ab + row*128 + (((h*4 + (lane>>4)) ^ (row & 7)) << 4));
      }
      #pragma unroll
      for (int j = 0; j < 4; ++j){
        int row = wn + j*16 + (lane & 15);
        bfr[j] = *(const bf16x8*)(Bb + row*128 + (((h*4 + (lane>>4)) ^ (row & 7)) << 4));
      }
      #pragma unroll
      for (int i = 0; i < 4; ++i)
        #pragma unroll
        for (int j = 0; j < 4; ++j)
          acc[i][j] = __builtin_amdgcn_mfma_f32_16x16x32_bf16(af[i], bfr[j], acc[i][j], 0, 0, 0);
    }
  };

  stage(0, 0);
  __syncthreads();
  for (int s = 0; s < NSTEP; ++s){
    if (s + 1 < NSTEP) stage((s+1) & 1, s+1);
    compute(s & 1);
    __syncthreads();
  }

  // ---- epilogue (C/D: col=lane&15 -> n, row=(lane>>4)*4+q -> m) ----
  if constexpr (CID==1){
    float badd = s0[0] + s1[0];
    #pragma unroll
    for (int i = 0; i < 4; ++i){
      int o = m0 + wm + i*16 + ((lane >> 4) << 2);
      #pragma unroll
      for (int j = 0; j < 4; ++j){
        uint32_t n = n0 + wn + j*16 + (lane & 15);
        uint32_t b = n / 196u, p = n - b*196u;
        uint32_t py = p / 14u, px = p - py*14u;
        size_t rn = (size_t)b*256 + (py+1)*16 + (px+1);
        ushort4 pk;
        #pragma unroll
        for (int q = 0; q < 4; ++q) ((u16*)&pk)[q] = f2bf(acc[i][j][q] + badd);
        *(ushort4*)(Obf + rn*256 + o) = pk;
      }
    }
  } else if constexpr (CID==2){
    float badd = s0[0] + s1[0];
    #pragma unroll
    for (int i = 0; i < 4; ++i){
      int o = m0 + wm + i*16 + ((lane >> 4) << 2);
      #pragma unroll
      for (int j = 0; j < 4; ++j){
        size_t n = n0 + wn + j*16 + (lane & 15);
        ushort4 pk;
        #pragma unroll
        for (int q = 0; q < 4; ++q) ((u16*)&pk)[q] = f2bf(acc[i][j][q] + badd);
        *(ushort4*)(Obf + n*256 + o) = pk;
      }
    }
  } else {
    float b3 = s0[0], rs = s1[0], rb = s2[0];
    #pragma unroll
    for (int i = 0; i < 4; ++i){
      int o = m0 + wm + i*16 + ((lane >> 4) << 2);
      #pragma unroll
      for (int j = 0; j < 4; ++j){
        uint32_t n = n0 + wn + j*16 + (lane & 15);
        uint32_t b = n / 196u, p = n - b*196u;
        size_t base = ((size_t)b*1024 + o)*196 + p;
        #pragma unroll
        for (int q = 0; q < 4; ++q){
          float v = (acc[i][j][q] + b3)*rs + rb + xres[base + (size_t)q*196];
          Of32[base + (size_t)q*196] = fmaxf(v, 0.f);
        }
      }
    }
  }
}

// ---------------------------------------------------------------------------
extern "C" void kernel_launch(void* const* d_in, const int* in_sizes, int n_in,
                              void* d_out, int out_size, void* d_ws, size_t ws_size,
                              hipStream_t stream){
  (void)in_sizes; (void)n_in; (void)out_size; (void)ws_size;
  const float* x   = (const float*)d_in[0];
  const float* w1  = (const float*)d_in[1];
  const float* w2  = (const float*)d_in[2];
  const float* w3  = (const float*)d_in[3];
  const float* b1b = (const float*)d_in[4];
  const float* b2a = (const float*)d_in[5];
  const float* b2b = (const float*)d_in[6];
  const float* b3a = (const float*)d_in[7];
  const float* b3b = (const float*)d_in[8];
  const float* rsc = (const float*)d_in[9];
  const float* rbi = (const float*)d_in[10];

  // ws layout (bytes):
  //   xp1 @ 0         : 32768 padded rows x 512B = 16.78 MB (conv2 input)
  //   xp2 @ 16777216  : 25088 rows x 512B = 12.85 MB (conv3 input)
  //   wb1 @ 29622272  : 512 KB
  //   wb2 @ 30146560  : 1.125 MB
  //   wb3 @ 31326208  : 512 KB
  char* ws  = (char*)d_ws;
  u16*  xp1 = (u16*)ws;
  u16*  xp2 = (u16*)(ws + 16777216);
  u16*  wb1 = (u16*)(ws + 29622272);
  u16*  wb2 = (u16*)(ws + 30146560);
  u16*  wb3 = (u16*)(ws + 31326208);
  u16*  xp0 = (u16*)d_out;   // conv1 input staged in d_out (dead before conv3 writes)

  cvt_f32_bf16<<<dim3(1024), 256, 0, stream>>>(w1, wb1, 262144);
  prep_w2k    <<<dim3(2304), 256, 0, stream>>>(w2, wb2);
  cvt_f32_bf16<<<dim3(1024), 256, 0, stream>>>(w3, wb3, 262144);
  transform_x <<<dim3(16,128), 256, 0, stream>>>(x, xp0);
  zfill_borders<<<dim3(960), 256, 0, stream>>>(xp1);

  gemm_k<1><<<dim3(196, 2), 256, 0, stream>>>(wb1, xp0, xp1, nullptr, nullptr, b1b, b2a, nullptr);
  gemm_k<2><<<dim3(196, 2), 256, 0, stream>>>(wb2, xp1, xp2, nullptr, nullptr, b2b, b3a, nullptr);
  gemm_k<3><<<dim3(196, 8), 256, 0, stream>>>(wb3, xp2, nullptr, (float*)d_out, x, b3b, rsc, rbi);
}